// Round 4
// baseline (432.688 us; speedup 1.0000x reference)
//
#include <hip/hip_runtime.h>
#include <math.h>

#define NSTEPS 256
#define GRIDN  160
#define NVOX   (160 * 160 * 160)

// One wave (64 lanes) per LOR; each lane handles 4 of the 256 steps.
// The entire geometry path must be plain f32 mul+add (NO fma contraction) to
// bit-match the harness's float32 numpy reference on every floor() decision.
__global__ __launch_bounds__(256) void trace_kernel(
    const float* __restrict__ image,
    const float* __restrict__ lors,
    float* __restrict__ bp,
    int n_lors)
{
#pragma clang fp contract(off)
    const int wave = (int)((blockIdx.x * blockDim.x + threadIdx.x) >> 6);
    const int lane = threadIdx.x & 63;
    if (wave >= n_lors) return;

    const float* l = lors + (size_t)wave * 7;
    const float p0x = l[0], p0y = l[1], p0z = l[2];
    const float dx = l[3] - p0x;
    const float dy = l[4] - p0y;
    const float dz = l[5] - p0z;
    const float tof = l[6];

    const float L  = sqrtf(dx * dx + dy * dy + dz * dz);
    const float dl = L * (1.0f / NSTEPS);
    const float s_tof = tof * 0.15f;                 // C_HALF
    const float SIGMA = (float)(45.0 / 2.355);       // f32(TIME_RES*C_HALF/2.355)

    int   flat[4];
    float w[4];
    float psum = 0.0f;

    #pragma unroll
    for (int k = 0; k < 4; ++k) {
        const int j = lane + 64 * k;
        const float t = (j + 0.5f) * (1.0f / NSTEPS);   // exact
        // pts = p0 + t*d, separate f32 mul then add (contract off => no fma)
        const float px = p0x + t * dx;
        const float py = p0y + t * dy;
        const float pz = p0z + t * dz;
        // idx = floor((p - ORIGIN)/VOXSIZE), ORIGIN=-160, VOXSIZE=2 (exact /2)
        const float fx = floorf((px + 160.0f) * 0.5f);
        const float fy = floorf((py + 160.0f) * 0.5f);
        const float fz = floorf((pz + 160.0f) * 0.5f);
        const bool inb = (fx >= 0.0f) & (fx < 160.0f) &
                         (fy >= 0.0f) & (fy < 160.0f) &
                         (fz >= 0.0f) & (fz < 160.0f);
        const float s = (t - 0.5f) * L;
        const float u = (s - s_tof) / SIGMA;
        const float e = 0.5f * (u * u);

        float wk = 0.0f;
        int   fl = 0;
        if (inb && e < 30.0f) {   // w < e^-30*dl ~ 1e-13, negligible vs thr=13.28
            wk = expf(-e) * dl;
            fl = (int)fx * (GRIDN * GRIDN) + (int)fy * GRIDN + (int)fz;
            psum += image[fl] * wk;
        }
        flat[k] = fl;
        w[k]    = wk;
    }

    // Wave-wide butterfly reduction (64 lanes)
    #pragma unroll
    for (int off = 32; off >= 1; off >>= 1)
        psum += __shfl_xor(psum, off, 64);

    #pragma unroll
    for (int k = 0; k < 4; ++k) {
        if (w[k] > 0.0f)
            atomicAdd(&bp[flat[k]], psum * w[k]);
    }
}

// out = image / (effmap + eps) * bp   (bp already resides in `out`)
__global__ __launch_bounds__(256) void finalize_kernel(
    const float4* __restrict__ image,
    const float4* __restrict__ effmap,
    float4* __restrict__ out,
    int n4)
{
    const int i = blockIdx.x * blockDim.x + threadIdx.x;
    if (i >= n4) return;
    const float4 im = image[i];
    const float4 ef = effmap[i];
    float4 b = out[i];
    b.x = im.x / (ef.x + 1e-8f) * b.x;
    b.y = im.y / (ef.y + 1e-8f) * b.y;
    b.z = im.z / (ef.z + 1e-8f) * b.z;
    b.w = im.w / (ef.w + 1e-8f) * b.w;
    out[i] = b;
}

extern "C" void kernel_launch(void* const* d_in, const int* in_sizes, int n_in,
                              void* d_out, int out_size, void* d_ws, size_t ws_size,
                              hipStream_t stream) {
    const float* image  = (const float*)d_in[0];
    const float* effmap = (const float*)d_in[1];
    const float* lors   = (const float*)d_in[2];
    float* out = (float*)d_out;

    const int n_lors = in_sizes[2] / 7;

    // bp accumulator lives in d_out; zero it (harness poisons with 0xAA)
    hipMemsetAsync(out, 0, (size_t)NVOX * sizeof(float), stream);

    // 4 waves per 256-thread block -> one LOR per wave
    const int waves_per_block = 256 / 64;
    const int blocks = (n_lors + waves_per_block - 1) / waves_per_block;
    trace_kernel<<<blocks, 256, 0, stream>>>(image, lors, out, n_lors);

    const int n4 = NVOX / 4;
    finalize_kernel<<<(n4 + 255) / 256, 256, 0, stream>>>(
        (const float4*)image, (const float4*)effmap, (float4*)out, n4);
}

// Round 5
// 314.706 us; speedup vs baseline: 1.3749x; 1.3749x over previous
//
#include <hip/hip_runtime.h>
#include <math.h>

#define NSTEPS 256
#define GRIDN  160
#define NVOX   (160 * 160 * 160)

// One wave (64 lanes) per LOR. Analytic window = (ray ∩ box) ∩ (Gaussian |u|<4.47σ),
// then only ceil(window/64) iterations of exact per-sample evaluation.
// Per-sample geometry is plain f32 mul+add (contract OFF) to bit-match the f32
// numpy reference on every floor()/bounds decision.
__global__ __launch_bounds__(256) void trace_kernel(
    const float* __restrict__ image,
    const float* __restrict__ lors,
    float* __restrict__ bp,
    int n_lors)
{
#pragma clang fp contract(off)
    const int wave = (int)((blockIdx.x * blockDim.x + threadIdx.x) >> 6);
    const int lane = threadIdx.x & 63;
    if (wave >= n_lors) return;

    const float* l = lors + (size_t)wave * 7;
    const float p0x = l[0], p0y = l[1], p0z = l[2];
    const float dx = l[3] - p0x;
    const float dy = l[4] - p0y;
    const float dz = l[5] - p0z;
    const float tof = l[6];

    const float L  = sqrtf(dx * dx + dy * dy + dz * dz);
    const float dl = L * (1.0f / NSTEPS);
    const float s_tof = tof * 0.15f;                 // C_HALF
    const float SIGMA = (float)(45.0 / 2.355);       // f32(TIME_RES*C_HALF/2.355)

    // ---- analytic window (conservative, ±2-step margin; per-sample checks stay exact)
    // Gaussian support: |s - s_tof| <= sqrt(2*10)*SIGMA  (e < 10)
    const float CUTS = 4.4721360f * SIGMA;
    float t0, t1;
    {
        const float invL = 1.0f / L;                 // L==0 -> inf/NaN, clamped below
        t0 = 0.5f + (s_tof - CUTS) * invL;
        t1 = 0.5f + (s_tof + CUTS) * invL;
        if (t0 > t1) { const float tmp = t0; t0 = t1; t1 = tmp; }
        // slab clip against box [-160,160]^3
        const float pc[3] = {p0x, p0y, p0z};
        const float dc[3] = {dx, dy, dz};
        #pragma unroll
        for (int a = 0; a < 3; ++a) {
            if (dc[a] != 0.0f) {
                const float inv = 1.0f / dc[a];
                const float ta = (-160.0f - pc[a]) * inv;
                const float tb = ( 160.0f - pc[a]) * inv;
                t0 = fmaxf(t0, fminf(ta, tb));
                t1 = fminf(t1, fmaxf(ta, tb));
            } else if (pc[a] < -160.0f || pc[a] >= 160.0f) {
                t1 = -1.0f;  // ray parallel to slab and outside: empty
            }
        }
        t0 = fmaxf(t0, 0.0f);
        t1 = fminf(t1, 1.0f);
    }
    int j0 = (int)floorf(t0 * 256.0f - 0.5f) - 2;
    int j1 = (int)ceilf (t1 * 256.0f - 0.5f) + 2;
    if (!(t0 <= t1)) { j0 = 0; j1 = -1; }            // NaN-safe empty
    j0 = max(j0, 0);
    j1 = min(j1, NSTEPS - 1);
    const int nk = (j1 - j0 + 64) >> 6;              // 0..4 iterations
    if (nk <= 0) return;                             // wave-uniform

    int   flat[4];
    float w[4];
    float psum = 0.0f;

    for (int k = 0; k < nk; ++k) {
        const int j = j0 + lane + (k << 6);
        const float t = (j + 0.5f) * (1.0f / NSTEPS);   // exact
        // pts = p0 + t*d, separate f32 mul then add (contract off => no fma)
        const float px = p0x + t * dx;
        const float py = p0y + t * dy;
        const float pz = p0z + t * dz;
        const float fx = floorf((px + 160.0f) * 0.5f);
        const float fy = floorf((py + 160.0f) * 0.5f);
        const float fz = floorf((pz + 160.0f) * 0.5f);
        const bool inb = (j <= j1) &
                         (fx >= 0.0f) & (fx < 160.0f) &
                         (fy >= 0.0f) & (fy < 160.0f) &
                         (fz >= 0.0f) & (fz < 160.0f);
        const float s = (t - 0.5f) * L;
        const float u = (s - s_tof) / SIGMA;
        const float e = 0.5f * (u * u);

        float wk = 0.0f;
        int   fl = 0;
        if (inb && e < 10.0f) {   // dropped tail ≤ ~5e-3/sample in bp, thr=13.28
            wk = expf(-e) * dl;
            fl = (int)fx * (GRIDN * GRIDN) + (int)fy * GRIDN + (int)fz;
            psum += image[fl] * wk;
        }
        flat[k] = fl;
        w[k]    = wk;
    }

    // Wave-wide butterfly reduction (64 lanes)
    #pragma unroll
    for (int off = 32; off >= 1; off >>= 1)
        psum += __shfl_xor(psum, off, 64);

    for (int k = 0; k < nk; ++k) {
        if (w[k] > 0.0f)
            atomicAdd(&bp[flat[k]], psum * w[k]);
    }
}

// out = image / (effmap + eps) * bp   (bp already resides in `out`)
__global__ __launch_bounds__(256) void finalize_kernel(
    const float4* __restrict__ image,
    const float4* __restrict__ effmap,
    float4* __restrict__ out,
    int n4)
{
    const int i = blockIdx.x * blockDim.x + threadIdx.x;
    if (i >= n4) return;
    const float4 im = image[i];
    const float4 ef = effmap[i];
    float4 b = out[i];
    b.x = im.x / (ef.x + 1e-8f) * b.x;
    b.y = im.y / (ef.y + 1e-8f) * b.y;
    b.z = im.z / (ef.z + 1e-8f) * b.z;
    b.w = im.w / (ef.w + 1e-8f) * b.w;
    out[i] = b;
}

extern "C" void kernel_launch(void* const* d_in, const int* in_sizes, int n_in,
                              void* d_out, int out_size, void* d_ws, size_t ws_size,
                              hipStream_t stream) {
    const float* image  = (const float*)d_in[0];
    const float* effmap = (const float*)d_in[1];
    const float* lors   = (const float*)d_in[2];
    float* out = (float*)d_out;

    const int n_lors = in_sizes[2] / 7;

    // bp accumulator lives in d_out; zero it (harness poisons with 0xAA)
    hipMemsetAsync(out, 0, (size_t)NVOX * sizeof(float), stream);

    // 4 waves per 256-thread block -> one LOR per wave
    const int waves_per_block = 256 / 64;
    const int blocks = (n_lors + waves_per_block - 1) / waves_per_block;
    trace_kernel<<<blocks, 256, 0, stream>>>(image, lors, out, n_lors);

    const int n4 = NVOX / 4;
    finalize_kernel<<<(n4 + 255) / 256, 256, 0, stream>>>(
        (const float4*)image, (const float4*)effmap, (float4*)out, n4);
}